// Round 5
// baseline (392.083 us; speedup 1.0000x reference)
//
#include <hip/hip_runtime.h>
#include <math.h>
#include <stdint.h>

#define CDIM 128
#define NTOT 4096

typedef _Float16 f16x8 __attribute__((ext_vector_type(8)));  // 8 fp16 (4 VGPRs)
typedef float floatx4 __attribute__((ext_vector_type(4)));   // MFMA accumulator

static __device__ __forceinline__ floatx4 mfma16(f16x8 a, f16x8 b, floatx4 c) {
    return __builtin_amdgcn_mfma_f32_16x16x32_f16(a, b, c, 0, 0, 0);
}
static __device__ __forceinline__ unsigned short f2h(float f) {
    _Float16 h = (_Float16)f;
    return __builtin_bit_cast(unsigned short, h);
}

// ---------------------------------------------------------------------------
// Fused q/k/v projection, MFMA. x: [4][128][4096] fp32.
// Outputs fp16: qo, ko: [b][n][c]; vo: [b][c][n].
// grid (64 n-tiles, 4 batches, 2 o-halves), 256 threads / 4 waves.
// Transpose-on-store staging (no fp32 LDS roundtrip). LDS 35 KB.
// ---------------------------------------------------------------------------
__global__ __launch_bounds__(256) void qkv_proj_kernel(
    const float* __restrict__ x,
    const float* __restrict__ Wq, const float* __restrict__ bq,
    const float* __restrict__ Wk, const float* __restrict__ bk,
    const float* __restrict__ Wv, const float* __restrict__ bv,
    unsigned short* __restrict__ qo, unsigned short* __restrict__ ko,
    unsigned short* __restrict__ vo)
{
    __shared__ __align__(16) unsigned short Xs[64][136];   // [n][c] fp16
    __shared__ __align__(16) unsigned short Ws[64][136];   // [o-half][c] fp16

    const int t = threadIdx.x, b = blockIdx.y, n0 = blockIdx.x * 64;
    const int zo = blockIdx.z * 64;
    const int w = t >> 6, quad = (t >> 4) & 3, l15 = t & 15;

    // stage x tile with transpose-on-store: thread covers 4n x 8c
    {
        const int n = (t & 15) * 4;
        const int c = (t >> 4) * 8;
        float4 xr[8];
        #pragma unroll
        for (int j = 0; j < 8; ++j)
            xr[j] = *(const float4*)&x[((size_t)b * CDIM + c + j) * NTOT + n0 + n];
        #pragma unroll
        for (int k = 0; k < 4; ++k) {
            ushort4 ulo, uhi;
            ulo.x = f2h(((const float*)&xr[0])[k]);
            ulo.y = f2h(((const float*)&xr[1])[k]);
            ulo.z = f2h(((const float*)&xr[2])[k]);
            ulo.w = f2h(((const float*)&xr[3])[k]);
            uhi.x = f2h(((const float*)&xr[4])[k]);
            uhi.y = f2h(((const float*)&xr[5])[k]);
            uhi.z = f2h(((const float*)&xr[6])[k]);
            uhi.w = f2h(((const float*)&xr[7])[k]);
            *(ushort4*)&Xs[n + k][c]     = ulo;
            *(ushort4*)&Xs[n + k][c + 4] = uhi;
        }
    }

    f16x8 xf[4];
    for (int s = 0; s < 3; ++s) {
        const float* W    = (s == 0) ? Wq : (s == 1) ? Wk : Wv;
        const float* bias = (s == 0) ? bq : (s == 1) ? bk : bv;
        if (s) __syncthreads();   // previous Ws readers done
        {
            int o = t >> 2, ch = (t & 3) * 32;
            #pragma unroll
            for (int i = 0; i < 8; ++i) {
                float4 f4 = *(const float4*)&W[(size_t)(zo + o) * CDIM + ch + i * 4];
                ushort4 u = { f2h(f4.x), f2h(f4.y), f2h(f4.z), f2h(f4.w) };
                *(ushort4*)&Ws[o][ch + i * 4] = u;
            }
        }
        __syncthreads();          // Ws (and on s==0, Xs) ready
        if (s == 0) {
            #pragma unroll
            for (int f = 0; f < 4; ++f)
                xf[f] = *(const f16x8*)&Xs[w * 16 + l15][f * 32 + quad * 8];
        }

        if (s < 2) {   // q, k: C[o][n], A = W, B = X
            unsigned short* dst = (s == 0) ? qo : ko;
            #pragma unroll
            for (int ot = 0; ot < 4; ++ot) {
                floatx4 acc = (floatx4){0.f, 0.f, 0.f, 0.f};
                #pragma unroll
                for (int f = 0; f < 4; ++f) {
                    f16x8 aW = *(const f16x8*)&Ws[ot * 16 + l15][f * 32 + quad * 8];
                    acc = mfma16(aW, xf[f], acc);
                }
                const int ob = zo + ot * 16 + quad * 4;
                ushort4 u;
                u.x = f2h(acc[0] + bias[ob + 0]);
                u.y = f2h(acc[1] + bias[ob + 1]);
                u.z = f2h(acc[2] + bias[ob + 2]);
                u.w = f2h(acc[3] + bias[ob + 3]);
                *(ushort4*)&dst[((size_t)b * NTOT + n0 + w * 16 + l15) * CDIM + ob] = u;
            }
        } else {       // v: C'[n][o], A = X, B = W
            #pragma unroll
            for (int ot = 0; ot < 4; ++ot) {
                floatx4 acc = (floatx4){0.f, 0.f, 0.f, 0.f};
                #pragma unroll
                for (int f = 0; f < 4; ++f) {
                    f16x8 bW = *(const f16x8*)&Ws[ot * 16 + l15][f * 32 + quad * 8];
                    acc = mfma16(xf[f], bW, acc);
                }
                const int o = zo + ot * 16 + l15;
                const float bv_ = bias[o];
                ushort4 u;
                u.x = f2h(acc[0] + bv_); u.y = f2h(acc[1] + bv_);
                u.z = f2h(acc[2] + bv_); u.w = f2h(acc[3] + bv_);
                *(ushort4*)&vo[((size_t)b * CDIM + o) * NTOT + n0 + w * 16 + quad * 4] = u;
            }
        }
    }
}

// ---------------------------------------------------------------------------
// Flash attention, wave-specialized. q,k: [b][n][128] fp16; v: [b][128][n]
// fp16; ao: [b][n][128] fp16. grid (64, 4), 256 threads / 4 waves.
// BQ=64 queries/block, KT=128 keys/iter, 32 iterations.
// Wave w: S for ALL 64 q x ITS 32 j (K rows wave-private, frags reused x4);
//         PV for ITS 32 d x all q (V rows wave-private).
// P exchanged via double-buffered LDS; wave-local-max P + per-chunk correction
// factors folded into PV B-fragments => exactly ONE barrier per iteration.
// K/V staged by owning wave with register prefetch of tile t+1.
// ---------------------------------------------------------------------------
__global__ __launch_bounds__(256, 1) void attn_kernel(
    const unsigned short* __restrict__ qg,
    const unsigned short* __restrict__ kg,
    const unsigned short* __restrict__ vg,
    unsigned short* __restrict__ aog)
{
    __shared__ __align__(16) unsigned short Ks[128 * 136];     // [j][c] 34.8 KB
    __shared__ __align__(16) unsigned short Vs[128 * 136];     // [d][j] 34.8 KB
    __shared__ __align__(16) unsigned short Ps[2][64 * 136];   // [i][j]  34.8 KB
    __shared__ float m_sh[2][4][64];
    __shared__ float l_sh[2][4][64];

    const int t = threadIdx.x;
    const int w = t >> 6, quad = (t >> 4) & 3, l15 = t & 15;
    const int b = blockIdx.y;
    const int i0 = blockIdx.x * 64;

    // Q B-fragments direct from global (held in regs all kernel)
    f16x8 bQ[4][4];
    #pragma unroll
    for (int it = 0; it < 4; ++it) {
        const size_t qrow = ((size_t)b * NTOT + i0 + it * 16 + l15) * CDIM;
        #pragma unroll
        for (int f = 0; f < 4; ++f)
            bQ[it][f] = *(const f16x8*)&qg[qrow + f * 32 + quad * 8];
    }

    // prefetch tile 0 (wave-private rows)
    uint4 bufK[8], bufV[8];
    {
        #pragma unroll
        for (int i = 0; i < 8; ++i) {
            bufK[i] = *(const uint4*)&kg[((size_t)b * NTOT + 0 + w * 32 + i * 4 + quad) * CDIM + l15 * 8];
            bufV[i] = *(const uint4*)&vg[((size_t)b * CDIM + w * 32 + i * 4 + quad) * NTOT + 0 + l15 * 8];
        }
    }

    floatx4 accO[2][4];   // [dt][it]
    #pragma unroll
    for (int dt = 0; dt < 2; ++dt)
        #pragma unroll
        for (int it = 0; it < 4; ++it) accO[dt][it] = (floatx4){0.f, 0.f, 0.f, 0.f};
    float m_run[4] = {-INFINITY, -INFINITY, -INFINITY, -INFINITY};
    float l_run[4] = {0.f, 0.f, 0.f, 0.f};

    for (int iter = 0; iter < 32; ++iter) {
        const int p = iter & 1;
        // --- commit staged tile (own rows; in-wave DS ordering, no barrier) ---
        #pragma unroll
        for (int i = 0; i < 8; ++i) {
            *(uint4*)&Ks[(w * 32 + i * 4 + quad) * 136 + l15 * 8] = bufK[i];
            *(uint4*)&Vs[(w * 32 + i * 4 + quad) * 136 + l15 * 8] = bufV[i];
        }
        // --- prefetch next tile ---
        {
            const int jn = (iter * 128 + 128) & (NTOT - 1);
            #pragma unroll
            for (int i = 0; i < 8; ++i) {
                bufK[i] = *(const uint4*)&kg[((size_t)b * NTOT + jn + w * 32 + i * 4 + quad) * CDIM + l15 * 8];
                bufV[i] = *(const uint4*)&vg[((size_t)b * CDIM + w * 32 + i * 4 + quad) * NTOT + jn + l15 * 8];
            }
        }

        // --- S = K_own · Q^T : accT[it][jl], C[row=j-local][col=i-local] ---
        floatx4 accT[4][2];
        #pragma unroll
        for (int it = 0; it < 4; ++it)
            #pragma unroll
            for (int jl = 0; jl < 2; ++jl) accT[it][jl] = (floatx4){0.f, 0.f, 0.f, 0.f};
        #pragma unroll
        for (int jl = 0; jl < 2; ++jl)
            #pragma unroll
            for (int f = 0; f < 4; ++f) {
                f16x8 aK = *(const f16x8*)&Ks[(w * 32 + jl * 16 + l15) * 136 + f * 32 + quad * 8];
                #pragma unroll
                for (int it = 0; it < 4; ++it)
                    accT[it][jl] = mfma16(aK, bQ[it][f], accT[it][jl]);
            }

        // --- wave-local softmax: per-lane stats for query (it, l15) ---
        #pragma unroll
        for (int it = 0; it < 4; ++it) {
            float m = accT[it][0][0];
            #pragma unroll
            for (int jl = 0; jl < 2; ++jl)
                #pragma unroll
                for (int r = 0; r < 4; ++r) m = fmaxf(m, accT[it][jl][r]);
            m = fmaxf(m, __shfl_xor(m, 16));
            m = fmaxf(m, __shfl_xor(m, 32));     // max over wave's 32 j
            float psum = 0.f;
            #pragma unroll
            for (int jl = 0; jl < 2; ++jl) {
                float p0 = __expf(accT[it][jl][0] - m);
                float p1 = __expf(accT[it][jl][1] - m);
                float p2 = __expf(accT[it][jl][2] - m);
                float p3 = __expf(accT[it][jl][3] - m);
                psum += (p0 + p1) + (p2 + p3);
                ushort4 u = { f2h(p0), f2h(p1), f2h(p2), f2h(p3) };
                *(ushort4*)&Ps[p][(it * 16 + l15) * 136 + w * 32 + jl * 16 + quad * 4] = u;
            }
            psum += __shfl_xor(psum, 16);
            psum += __shfl_xor(psum, 32);
            if (quad == 0) {
                m_sh[p][w][it * 16 + l15] = m;
                l_sh[p][w][it * 16 + l15] = psum;
            }
        }
        __syncthreads();   // the ONLY barrier: Ps/m_sh/l_sh[p] visible

        // --- merge stats (every wave, per lane) + correction factors ---
        float cf[4][4];   // [src-wave chunk][it]
        #pragma unroll
        for (int it = 0; it < 4; ++it) {
            const int qi = it * 16 + l15;
            float m0 = m_sh[p][0][qi], m1 = m_sh[p][1][qi];
            float m2 = m_sh[p][2][qi], m3 = m_sh[p][3][qi];
            float mt = fmaxf(fmaxf(m0, m1), fmaxf(m2, m3));
            float mn = fmaxf(m_run[it], mt);
            float alpha = __expf(m_run[it] - mn);   // 0 on first tile
            m_run[it] = mn;
            float c0 = __expf(m0 - mn), c1 = __expf(m1 - mn);
            float c2 = __expf(m2 - mn), c3 = __expf(m3 - mn);
            cf[0][it] = c0; cf[1][it] = c1; cf[2][it] = c2; cf[3][it] = c3;
            l_run[it] = l_run[it] * alpha
                      + l_sh[p][0][qi] * c0 + l_sh[p][1][qi] * c1
                      + l_sh[p][2][qi] * c2 + l_sh[p][3][qi] * c3;
            accO[0][it][0] *= alpha; accO[0][it][1] *= alpha;
            accO[0][it][2] *= alpha; accO[0][it][3] *= alpha;
            accO[1][it][0] *= alpha; accO[1][it][1] *= alpha;
            accO[1][it][2] *= alpha; accO[1][it][3] *= alpha;
        }

        // --- O^T += V_own · P^T, B-frags scaled by cf ---
        f16x8 aV[2][4];
        #pragma unroll
        for (int dt = 0; dt < 2; ++dt)
            #pragma unroll
            for (int kb = 0; kb < 4; ++kb)
                aV[dt][kb] = *(const f16x8*)&Vs[(w * 32 + dt * 16 + l15) * 136 + kb * 32 + quad * 8];
        #pragma unroll
        for (int it = 0; it < 4; ++it)
            #pragma unroll
            for (int kb = 0; kb < 4; ++kb) {
                f16x8 bP = *(const f16x8*)&Ps[p][(it * 16 + l15) * 136 + kb * 32 + quad * 8];
                _Float16 cs = (_Float16)cf[kb][it];
                f16x8 cv = { cs, cs, cs, cs, cs, cs, cs, cs };
                bP = bP * cv;
                accO[0][it] = mfma16(aV[0][kb], bP, accO[0][it]);
                accO[1][it] = mfma16(aV[1][kb], bP, accO[1][it]);
            }
    }

    // --- store O^T[d][i] as ao[b][i][d] fp16 ---
    #pragma unroll
    for (int it = 0; it < 4; ++it) {
        const float inv = 1.0f / l_run[it];
        const size_t orow = ((size_t)b * NTOT + i0 + it * 16 + l15) * CDIM;
        #pragma unroll
        for (int dt = 0; dt < 2; ++dt) {
            ushort4 u;
            u.x = f2h(accO[dt][it][0] * inv);
            u.y = f2h(accO[dt][it][1] * inv);
            u.z = f2h(accO[dt][it][2] * inv);
            u.w = f2h(accO[dt][it][3] * inv);
            *(ushort4*)&aog[orow + w * 32 + dt * 16 + quad * 4] = u;
        }
    }
}

// ---------------------------------------------------------------------------
// Output projection + residual, MFMA. ao: [b][n][128] fp16.
// out[b][o][n] = Wo·ao^T + bo + x. grid (64, 4, 2 o-halves), 256 threads.
// ---------------------------------------------------------------------------
__global__ __launch_bounds__(256) void out_proj_kernel(
    const unsigned short* __restrict__ ao,
    const float* __restrict__ Wo, const float* __restrict__ bo,
    const float* __restrict__ x, float* __restrict__ out)
{
    __shared__ __align__(16) unsigned short As[64][136];  // [n][c]
    __shared__ __align__(16) unsigned short Ws[64][136];  // [o-half][c]

    const int t = threadIdx.x, b = blockIdx.y, n0 = blockIdx.x * 64;
    const int zo = blockIdx.z * 64;
    const int w = t >> 6, quad = (t >> 4) & 3, l15 = t & 15;

    #pragma unroll
    for (int r = 0; r < 4; ++r) {   // stage ao tile (direct fp16 copy)
        int flat = r * 256 + t;
        int row = flat >> 4, c16 = (flat & 15) * 8;
        *(uint4*)&As[row][c16] =
            *(const uint4*)&ao[((size_t)b * NTOT + n0 + row) * CDIM + c16];
    }
    {
        int o = t >> 2, ch = (t & 3) * 32;
        #pragma unroll
        for (int i = 0; i < 8; ++i) {
            float4 f4 = *(const float4*)&Wo[(size_t)(zo + o) * CDIM + ch + i * 4];
            ushort4 u = { f2h(f4.x), f2h(f4.y), f2h(f4.z), f2h(f4.w) };
            *(ushort4*)&Ws[o][ch + i * 4] = u;
        }
    }
    __syncthreads();

    f16x8 bA[4];
    #pragma unroll
    for (int f = 0; f < 4; ++f)
        bA[f] = *(const f16x8*)&As[w * 16 + l15][f * 32 + quad * 8];

    #pragma unroll
    for (int ot = 0; ot < 4; ++ot) {
        floatx4 acc = (floatx4){0.f, 0.f, 0.f, 0.f};
        #pragma unroll
        for (int f = 0; f < 4; ++f) {
            f16x8 aW = *(const f16x8*)&Ws[ot * 16 + l15][f * 32 + quad * 8];
            acc = mfma16(aW, bA[f], acc);
        }
        const int ob = zo + ot * 16 + quad * 4;
        #pragma unroll
        for (int r = 0; r < 4; ++r) {
            size_t idx = ((size_t)b * CDIM + ob + r) * NTOT + n0 + w * 16 + l15;
            out[idx] = acc[r] + bo[ob + r] + x[idx];
        }
    }
}

// ---------------------------------------------------------------------------
extern "C" void kernel_launch(void* const* d_in, const int* in_sizes, int n_in,
                              void* d_out, int out_size, void* d_ws, size_t ws_size,
                              hipStream_t stream)
{
    const float* x  = (const float*)d_in[0];
    const float* Wq = (const float*)d_in[1];
    const float* bq = (const float*)d_in[2];
    const float* Wk = (const float*)d_in[3];
    const float* bk = (const float*)d_in[4];
    const float* Wv = (const float*)d_in[5];
    const float* bv = (const float*)d_in[6];
    const float* Wo = (const float*)d_in[7];
    const float* bo = (const float*)d_in[8];
    float* out = (float*)d_out;

    const size_t PER = (size_t)4 * CDIM * NTOT;   // 2,097,152 elements
    unsigned short* q_ws  = (unsigned short*)d_ws;
    unsigned short* k_ws  = q_ws + PER;
    unsigned short* v_ws  = k_ws + PER;
    unsigned short* ao_ws = v_ws + PER;           // fp16 [b][n][c]

    dim3 blk(256);
    qkv_proj_kernel<<<dim3(64, 4, 2), blk, 0, stream>>>(
        x, Wq, bq, Wk, bk, Wv, bv, q_ws, k_ws, v_ws);
    attn_kernel<<<dim3(64, 4), blk, 0, stream>>>(q_ws, k_ws, v_ws, ao_ws);
    out_proj_kernel<<<dim3(64, 4, 2), blk, 0, stream>>>(ao_ws, Wo, bo, x, out);
}

// Round 6
// 268.394 us; speedup vs baseline: 1.4608x; 1.4608x over previous
//
#include <hip/hip_runtime.h>
#include <math.h>
#include <stdint.h>

#define CDIM 128
#define NTOT 4096

typedef _Float16 f16x8 __attribute__((ext_vector_type(8)));  // 8 fp16 (4 VGPRs)
typedef float floatx4 __attribute__((ext_vector_type(4)));   // MFMA accumulator

static __device__ __forceinline__ floatx4 mfma16(f16x8 a, f16x8 b, floatx4 c) {
    return __builtin_amdgcn_mfma_f32_16x16x32_f16(a, b, c, 0, 0, 0);
}
static __device__ __forceinline__ unsigned short f2h(float f) {
    _Float16 h = (_Float16)f;
    return __builtin_bit_cast(unsigned short, h);
}
static __device__ __forceinline__ float h2f(unsigned short u) {
    return (float)__builtin_bit_cast(_Float16, u);
}

// ---------------------------------------------------------------------------
// Fused q/k/v projection, MFMA. x: [4][128][4096] fp32.
// Outputs fp16: qo, ko: [b][n][c]; vo: [b][c][n].
// grid (64 n-tiles, 4 batches, 2 o-halves), 256 threads / 4 waves.
// ---------------------------------------------------------------------------
__global__ __launch_bounds__(256) void qkv_proj_kernel(
    const float* __restrict__ x,
    const float* __restrict__ Wq, const float* __restrict__ bq,
    const float* __restrict__ Wk, const float* __restrict__ bk,
    const float* __restrict__ Wv, const float* __restrict__ bv,
    unsigned short* __restrict__ qo, unsigned short* __restrict__ ko,
    unsigned short* __restrict__ vo)
{
    __shared__ __align__(16) unsigned short Xs[64][136];   // [n][c] fp16
    __shared__ __align__(16) unsigned short Ws[64][136];   // [o-half][c] fp16

    const int t = threadIdx.x, b = blockIdx.y, n0 = blockIdx.x * 64;
    const int zo = blockIdx.z * 64;
    const int w = t >> 6, quad = (t >> 4) & 3, l15 = t & 15;

    // stage x tile with transpose-on-store: thread covers 4n x 8c
    {
        const int n = (t & 15) * 4;
        const int c = (t >> 4) * 8;
        float4 xr[8];
        #pragma unroll
        for (int j = 0; j < 8; ++j)
            xr[j] = *(const float4*)&x[((size_t)b * CDIM + c + j) * NTOT + n0 + n];
        #pragma unroll
        for (int k = 0; k < 4; ++k) {
            ushort4 ulo, uhi;
            ulo.x = f2h(((const float*)&xr[0])[k]);
            ulo.y = f2h(((const float*)&xr[1])[k]);
            ulo.z = f2h(((const float*)&xr[2])[k]);
            ulo.w = f2h(((const float*)&xr[3])[k]);
            uhi.x = f2h(((const float*)&xr[4])[k]);
            uhi.y = f2h(((const float*)&xr[5])[k]);
            uhi.z = f2h(((const float*)&xr[6])[k]);
            uhi.w = f2h(((const float*)&xr[7])[k]);
            *(ushort4*)&Xs[n + k][c]     = ulo;
            *(ushort4*)&Xs[n + k][c + 4] = uhi;
        }
    }

    f16x8 xf[4];
    for (int s = 0; s < 3; ++s) {
        const float* W    = (s == 0) ? Wq : (s == 1) ? Wk : Wv;
        const float* bias = (s == 0) ? bq : (s == 1) ? bk : bv;
        if (s) __syncthreads();   // previous Ws readers done
        {
            int o = t >> 2, ch = (t & 3) * 32;
            #pragma unroll
            for (int i = 0; i < 8; ++i) {
                float4 f4 = *(const float4*)&W[(size_t)(zo + o) * CDIM + ch + i * 4];
                ushort4 u = { f2h(f4.x), f2h(f4.y), f2h(f4.z), f2h(f4.w) };
                *(ushort4*)&Ws[o][ch + i * 4] = u;
            }
        }
        __syncthreads();          // Ws (and on s==0, Xs) ready
        if (s == 0) {
            #pragma unroll
            for (int f = 0; f < 4; ++f)
                xf[f] = *(const f16x8*)&Xs[w * 16 + l15][f * 32 + quad * 8];
        }

        if (s < 2) {   // q, k: C[o][n], A = W, B = X
            unsigned short* dst = (s == 0) ? qo : ko;
            #pragma unroll
            for (int ot = 0; ot < 4; ++ot) {
                floatx4 acc = (floatx4){0.f, 0.f, 0.f, 0.f};
                #pragma unroll
                for (int f = 0; f < 4; ++f) {
                    f16x8 aW = *(const f16x8*)&Ws[ot * 16 + l15][f * 32 + quad * 8];
                    acc = mfma16(aW, xf[f], acc);
                }
                const int ob = zo + ot * 16 + quad * 4;
                ushort4 u;
                u.x = f2h(acc[0] + bias[ob + 0]);
                u.y = f2h(acc[1] + bias[ob + 1]);
                u.z = f2h(acc[2] + bias[ob + 2]);
                u.w = f2h(acc[3] + bias[ob + 3]);
                *(ushort4*)&dst[((size_t)b * NTOT + n0 + w * 16 + l15) * CDIM + ob] = u;
            }
        } else {       // v: C'[n][o], A = X, B = W
            #pragma unroll
            for (int ot = 0; ot < 4; ++ot) {
                floatx4 acc = (floatx4){0.f, 0.f, 0.f, 0.f};
                #pragma unroll
                for (int f = 0; f < 4; ++f) {
                    f16x8 bW = *(const f16x8*)&Ws[ot * 16 + l15][f * 32 + quad * 8];
                    acc = mfma16(xf[f], bW, acc);
                }
                const int o = zo + ot * 16 + l15;
                const float bv_ = bias[o];
                ushort4 u;
                u.x = f2h(acc[0] + bv_); u.y = f2h(acc[1] + bv_);
                u.z = f2h(acc[2] + bv_); u.w = f2h(acc[3] + bv_);
                *(ushort4*)&vo[((size_t)b * CDIM + o) * NTOT + n0 + w * 16 + quad * 4] = u;
            }
        }
    }
}

// ---------------------------------------------------------------------------
// Flash attention, R4 structure + split-K(2) + Ps-overlay + reg prefetch.
// q,k: [b][n][128] fp16; v: [b][128][n] fp16.
// grid (64 q-tiles, 4 batches, 2 key-halves), 256 threads / 4 waves.
// Wave w owns queries i = w*16+l15 end-to-end (S, softmax, PV all q-split);
// KT=128 keys/iter, 16 iters over this block's 2048-key half.
// Ps (per-wave [16][136]) overlaid on Ks rows 0..63 (freed after barrier C).
// Outputs: Op[z][b][i][d] fp16 (partial O, normalized by own l), Ms/Ls fp32.
// ---------------------------------------------------------------------------
__global__ __launch_bounds__(256, 2) void attn_kernel(
    const unsigned short* __restrict__ qg,
    const unsigned short* __restrict__ kg,
    const unsigned short* __restrict__ vg,
    unsigned short* __restrict__ Op,
    float* __restrict__ Ms, float* __restrict__ Ls)
{
    __shared__ __align__(16) unsigned short Ks[128 * 136];   // [j][c] 34 KB (rows 0..63 reused as Ps)
    __shared__ __align__(16) unsigned short Vs[128 * 136];   // [d][j] 34 KB

    const int t = threadIdx.x;
    const int w = t >> 6, quad = (t >> 4) & 3, l15 = t & 15;
    const int b = blockIdx.y;
    const int i0 = blockIdx.x * 64;
    const int z = blockIdx.z;
    const int jbase = z * 2048;
    const size_t vbase = (size_t)b * CDIM * NTOT;
    unsigned short* PsW = &Ks[(size_t)w * 16 * 136];   // wave-private P region

    // Q B-fragments direct from global: B[k=c][n=i], i = w*16+l15
    f16x8 bQ[4];
    {
        const size_t qrow = ((size_t)b * NTOT + i0 + w * 16 + l15) * CDIM;
        #pragma unroll
        for (int f = 0; f < 4; ++f)
            bQ[f] = *(const f16x8*)&qg[qrow + f * 32 + quad * 8];
    }

    // prefetch tile 0 into registers
    uint4 bufK[8], bufV[8];
    {
        const size_t kb_ = ((size_t)b * NTOT + jbase) * CDIM;
        #pragma unroll
        for (int r = 0; r < 8; ++r) {
            int flat = r * 256 + t;
            int row = flat >> 4, c16 = (flat & 15) * 8;
            bufK[r] = *(const uint4*)&kg[kb_ + (size_t)row * CDIM + c16];
            bufV[r] = *(const uint4*)&vg[vbase + (size_t)row * NTOT + jbase + c16];
        }
    }

    floatx4 accO[8];
    #pragma unroll
    for (int dt = 0; dt < 8; ++dt) accO[dt] = (floatx4){0.f, 0.f, 0.f, 0.f};
    float m_run = -INFINITY, l_part = 0.f;

    for (int iter = 0; iter < 16; ++iter) {
        __syncthreads();   // (A) prev iter's PV reads of Vs/Ps done
        // commit prefetched tile to LDS
        #pragma unroll
        for (int r = 0; r < 8; ++r) {
            int flat = r * 256 + t;
            int row = flat >> 4, c16 = (flat & 15) * 8;
            *(uint4*)&Ks[row * 136 + c16] = bufK[r];
            *(uint4*)&Vs[row * 136 + c16] = bufV[r];
        }
        __syncthreads();   // (B) tiles ready

        // --- T^T[j][i] = K·Q^T : 8 j-tiles (reads ALL Ks rows) ---
        floatx4 accT[8];
        #pragma unroll
        for (int jt = 0; jt < 8; ++jt) {
            accT[jt] = (floatx4){0.f, 0.f, 0.f, 0.f};
            #pragma unroll
            for (int f = 0; f < 4; ++f) {
                f16x8 aK = *(const f16x8*)&Ks[(jt * 16 + l15) * 136 + f * 32 + quad * 8];
                accT[jt] = mfma16(aK, bQ[f], accT[jt]);
            }
        }

        // --- prefetch next tile (latency hidden behind softmax + PV) ---
        {
            const int jn = jbase + ((iter + 1) & 15) * 128;
            const size_t kb_ = ((size_t)b * NTOT + jn) * CDIM;
            #pragma unroll
            for (int r = 0; r < 8; ++r) {
                int flat = r * 256 + t;
                int row = flat >> 4, c16 = (flat & 15) * 8;
                bufK[r] = *(const uint4*)&kg[kb_ + (size_t)row * CDIM + c16];
                bufV[r] = *(const uint4*)&vg[vbase + (size_t)row * NTOT + jn + c16];
            }
        }

        // --- online softmax (per-lane; lane = one query) ---
        float tm = accT[0][0];
        #pragma unroll
        for (int jt = 0; jt < 8; ++jt)
            #pragma unroll
            for (int r = 0; r < 4; ++r) tm = fmaxf(tm, accT[jt][r]);
        tm = fmaxf(tm, __shfl_xor(tm, 16));
        tm = fmaxf(tm, __shfl_xor(tm, 32));
        const float m_new = fmaxf(m_run, tm);
        const float alpha = __expf(m_run - m_new);   // 0 on first tile
        m_run = m_new;

        float psum = 0.f;
        ushort4 pu[8];   // packed P held in regs until barrier C
        #pragma unroll
        for (int jt = 0; jt < 8; ++jt) {
            float p0 = __expf(accT[jt][0] - m_new);
            float p1 = __expf(accT[jt][1] - m_new);
            float p2 = __expf(accT[jt][2] - m_new);
            float p3 = __expf(accT[jt][3] - m_new);
            psum += (p0 + p1) + (p2 + p3);
            pu[jt].x = f2h(p0); pu[jt].y = f2h(p1);
            pu[jt].z = f2h(p2); pu[jt].w = f2h(p3);
        }
        l_part = l_part * alpha + psum;
        #pragma unroll
        for (int dt = 0; dt < 8; ++dt) {
            accO[dt][0] *= alpha; accO[dt][1] *= alpha;
            accO[dt][2] *= alpha; accO[dt][3] *= alpha;
        }

        __syncthreads();   // (C) all waves' S reads of Ks done -> Ps overlay safe
        #pragma unroll
        for (int jt = 0; jt < 8; ++jt)
            *(ushort4*)&PsW[l15 * 136 + jt * 16 + quad * 4] = pu[jt];

        // --- O^T += V^T·P^T (wave-private P; in-wave lgkmcnt ordering) ---
        f16x8 bP[4];
        #pragma unroll
        for (int kb = 0; kb < 4; ++kb)
            bP[kb] = *(const f16x8*)&PsW[l15 * 136 + kb * 32 + quad * 8];
        #pragma unroll
        for (int dt = 0; dt < 8; ++dt)
            #pragma unroll
            for (int kb = 0; kb < 4; ++kb) {
                f16x8 aV = *(const f16x8*)&Vs[(dt * 16 + l15) * 136 + kb * 32 + quad * 8];
                accO[dt] = mfma16(aV, bP[kb], accO[dt]);
            }
    }

    // final l over quads; store normalized partial + stats
    float lf = l_part;
    lf += __shfl_xor(lf, 16);
    lf += __shfl_xor(lf, 32);
    const float inv = 1.0f / lf;
    const size_t orow = (((size_t)z * 4 + b) * NTOT + i0 + w * 16 + l15) * CDIM;
    #pragma unroll
    for (int dt = 0; dt < 8; ++dt) {
        ushort4 u;
        u.x = f2h(accO[dt][0] * inv); u.y = f2h(accO[dt][1] * inv);
        u.z = f2h(accO[dt][2] * inv); u.w = f2h(accO[dt][3] * inv);
        *(ushort4*)&Op[orow + dt * 16 + quad * 4] = u;
    }
    if (quad == 0) {
        const int idx = (z * 4 + b) * NTOT + i0 + w * 16 + l15;
        Ms[idx] = m_run;
        Ls[idx] = lf;
    }
}

// ---------------------------------------------------------------------------
// Merge the two key-half partials: ao = (w0*O0 + w1*O1), wz = lz*e^{mz-M}/sum.
// grid 1024 x 256 threads, 8 halves (16 B) per thread.
// ---------------------------------------------------------------------------
__global__ __launch_bounds__(256) void combine_kernel(
    const unsigned short* __restrict__ Op,
    const float* __restrict__ Ms, const float* __restrict__ Ls,
    unsigned short* __restrict__ ao)
{
    const int tid = blockIdx.x * 256 + threadIdx.x;     // 0..262143
    const size_t e8 = (size_t)tid * 8;
    const int bn = tid >> 4;                            // b*4096+n (16 thr/row)
    const float m0 = Ms[bn], m1 = Ms[bn + 16384];
    const float l0 = Ls[bn], l1 = Ls[bn + 16384];
    const float M  = fmaxf(m0, m1);
    float w0 = l0 * __expf(m0 - M);
    float w1 = l1 * __expf(m1 - M);
    const float inv = 1.0f / (w0 + w1);
    w0 *= inv; w1 *= inv;

    uint4 a = *(const uint4*)&Op[e8];
    uint4 c = *(const uint4*)&Op[(size_t)2097152 + e8];
    const unsigned short* pa = (const unsigned short*)&a;
    const unsigned short* pc = (const unsigned short*)&c;
    unsigned short ov[8];
    #pragma unroll
    for (int j = 0; j < 8; ++j)
        ov[j] = f2h(w0 * h2f(pa[j]) + w1 * h2f(pc[j]));
    *(uint4*)&ao[e8] = *(const uint4*)ov;
}

// ---------------------------------------------------------------------------
// Output projection + residual, MFMA. ao: [b][n][128] fp16.
// out[b][o][n] = Wo·ao^T + bo + x. grid (64, 4, 2 o-halves), 256 threads.
// ---------------------------------------------------------------------------
__global__ __launch_bounds__(256) void out_proj_kernel(
    const unsigned short* __restrict__ ao,
    const float* __restrict__ Wo, const float* __restrict__ bo,
    const float* __restrict__ x, float* __restrict__ out)
{
    __shared__ __align__(16) unsigned short As[64][136];  // [n][c]
    __shared__ __align__(16) unsigned short Ws[64][136];  // [o-half][c]

    const int t = threadIdx.x, b = blockIdx.y, n0 = blockIdx.x * 64;
    const int zo = blockIdx.z * 64;
    const int w = t >> 6, quad = (t >> 4) & 3, l15 = t & 15;

    #pragma unroll
    for (int r = 0; r < 4; ++r) {   // stage ao tile (direct fp16 copy)
        int flat = r * 256 + t;
        int row = flat >> 4, c16 = (flat & 15) * 8;
        *(uint4*)&As[row][c16] =
            *(const uint4*)&ao[((size_t)b * NTOT + n0 + row) * CDIM + c16];
    }
    {
        int o = t >> 2, ch = (t & 3) * 32;
        #pragma unroll
        for (int i = 0; i < 8; ++i) {
            float4 f4 = *(const float4*)&Wo[(size_t)(zo + o) * CDIM + ch + i * 4];
            ushort4 u = { f2h(f4.x), f2h(f4.y), f2h(f4.z), f2h(f4.w) };
            *(ushort4*)&Ws[o][ch + i * 4] = u;
        }
    }
    __syncthreads();

    f16x8 bA[4];
    #pragma unroll
    for (int f = 0; f < 4; ++f)
        bA[f] = *(const f16x8*)&As[w * 16 + l15][f * 32 + quad * 8];

    #pragma unroll
    for (int ot = 0; ot < 4; ++ot) {
        floatx4 acc = (floatx4){0.f, 0.f, 0.f, 0.f};
        #pragma unroll
        for (int f = 0; f < 4; ++f) {
            f16x8 aW = *(const f16x8*)&Ws[ot * 16 + l15][f * 32 + quad * 8];
            acc = mfma16(aW, bA[f], acc);
        }
        const int ob = zo + ot * 16 + quad * 4;
        #pragma unroll
        for (int r = 0; r < 4; ++r) {
            size_t idx = ((size_t)b * CDIM + ob + r) * NTOT + n0 + w * 16 + l15;
            out[idx] = acc[r] + bo[ob + r] + x[idx];
        }
    }
}

// ---------------------------------------------------------------------------
extern "C" void kernel_launch(void* const* d_in, const int* in_sizes, int n_in,
                              void* d_out, int out_size, void* d_ws, size_t ws_size,
                              hipStream_t stream)
{
    const float* x  = (const float*)d_in[0];
    const float* Wq = (const float*)d_in[1];
    const float* bq = (const float*)d_in[2];
    const float* Wk = (const float*)d_in[3];
    const float* bk = (const float*)d_in[4];
    const float* Wv = (const float*)d_in[5];
    const float* bv = (const float*)d_in[6];
    const float* Wo = (const float*)d_in[7];
    const float* bo = (const float*)d_in[8];
    float* out = (float*)d_out;

    const size_t PER = (size_t)4 * CDIM * NTOT;   // 2,097,152 elements
    unsigned short* q_ws  = (unsigned short*)d_ws;
    unsigned short* k_ws  = q_ws + PER;
    unsigned short* v_ws  = k_ws + PER;
    unsigned short* ao_ws = v_ws + PER;           // fp16 [b][n][c]
    unsigned short* op_ws = ao_ws + PER;          // fp16 [2][b][n][c] partials
    float*          ms_ws = (float*)(op_ws + 2 * PER);   // [2][b*n]
    float*          ls_ws = ms_ws + 2 * 16384;

    dim3 blk(256);
    qkv_proj_kernel<<<dim3(64, 4, 2), blk, 0, stream>>>(
        x, Wq, bq, Wk, bk, Wv, bv, q_ws, k_ws, v_ws);
    attn_kernel<<<dim3(64, 4, 2), blk, 0, stream>>>(
        q_ws, k_ws, v_ws, op_ws, ms_ws, ls_ws);
    combine_kernel<<<dim3(1024), blk, 0, stream>>>(op_ws, ms_ws, ls_ws, ao_ws);
    out_proj_kernel<<<dim3(64, 4, 2), blk, 0, stream>>>(ao_ws, Wo, bo, x, out);
}

// Round 7
// 263.639 us; speedup vs baseline: 1.4872x; 1.0180x over previous
//
#include <hip/hip_runtime.h>
#include <math.h>
#include <stdint.h>

#define CDIM 128
#define NTOT 4096

typedef _Float16 f16x8 __attribute__((ext_vector_type(8)));  // 8 fp16 (4 VGPRs)
typedef float floatx4 __attribute__((ext_vector_type(4)));   // MFMA accumulator

static __device__ __forceinline__ floatx4 mfma16(f16x8 a, f16x8 b, floatx4 c) {
    return __builtin_amdgcn_mfma_f32_16x16x32_f16(a, b, c, 0, 0, 0);
}
static __device__ __forceinline__ unsigned short f2h(float f) {
    _Float16 h = (_Float16)f;
    return __builtin_bit_cast(unsigned short, h);
}
static __device__ __forceinline__ float h2f(unsigned short u) {
    return (float)__builtin_bit_cast(_Float16, u);
}

// ---------------------------------------------------------------------------
// Fused q/k/v projection, MFMA. x: [4][128][4096] fp32.
// Outputs fp16: qo, ko: [b][n][c]; vo: [b][c][n].
// grid (64 n-tiles, 4 batches, 2 o-halves), 256 threads / 4 waves.
// ---------------------------------------------------------------------------
__global__ __launch_bounds__(256) void qkv_proj_kernel(
    const float* __restrict__ x,
    const float* __restrict__ Wq, const float* __restrict__ bq,
    const float* __restrict__ Wk, const float* __restrict__ bk,
    const float* __restrict__ Wv, const float* __restrict__ bv,
    unsigned short* __restrict__ qo, unsigned short* __restrict__ ko,
    unsigned short* __restrict__ vo)
{
    __shared__ __align__(16) unsigned short Xs[64][136];   // [n][c] fp16
    __shared__ __align__(16) unsigned short Ws[64][136];   // [o-half][c] fp16

    const int t = threadIdx.x, b = blockIdx.y, n0 = blockIdx.x * 64;
    const int zo = blockIdx.z * 64;
    const int w = t >> 6, quad = (t >> 4) & 3, l15 = t & 15;

    // stage x tile with transpose-on-store: thread covers 4n x 8c
    {
        const int n = (t & 15) * 4;
        const int c = (t >> 4) * 8;
        float4 xr[8];
        #pragma unroll
        for (int j = 0; j < 8; ++j)
            xr[j] = *(const float4*)&x[((size_t)b * CDIM + c + j) * NTOT + n0 + n];
        #pragma unroll
        for (int k = 0; k < 4; ++k) {
            ushort4 ulo, uhi;
            ulo.x = f2h(((const float*)&xr[0])[k]);
            ulo.y = f2h(((const float*)&xr[1])[k]);
            ulo.z = f2h(((const float*)&xr[2])[k]);
            ulo.w = f2h(((const float*)&xr[3])[k]);
            uhi.x = f2h(((const float*)&xr[4])[k]);
            uhi.y = f2h(((const float*)&xr[5])[k]);
            uhi.z = f2h(((const float*)&xr[6])[k]);
            uhi.w = f2h(((const float*)&xr[7])[k]);
            *(ushort4*)&Xs[n + k][c]     = ulo;
            *(ushort4*)&Xs[n + k][c + 4] = uhi;
        }
    }

    f16x8 xf[4];
    for (int s = 0; s < 3; ++s) {
        const float* W    = (s == 0) ? Wq : (s == 1) ? Wk : Wv;
        const float* bias = (s == 0) ? bq : (s == 1) ? bk : bv;
        if (s) __syncthreads();   // previous Ws readers done
        {
            int o = t >> 2, ch = (t & 3) * 32;
            #pragma unroll
            for (int i = 0; i < 8; ++i) {
                float4 f4 = *(const float4*)&W[(size_t)(zo + o) * CDIM + ch + i * 4];
                ushort4 u = { f2h(f4.x), f2h(f4.y), f2h(f4.z), f2h(f4.w) };
                *(ushort4*)&Ws[o][ch + i * 4] = u;
            }
        }
        __syncthreads();          // Ws (and on s==0, Xs) ready
        if (s == 0) {
            #pragma unroll
            for (int f = 0; f < 4; ++f)
                xf[f] = *(const f16x8*)&Xs[w * 16 + l15][f * 32 + quad * 8];
        }

        if (s < 2) {   // q, k: C[o][n], A = W, B = X
            unsigned short* dst = (s == 0) ? qo : ko;
            #pragma unroll
            for (int ot = 0; ot < 4; ++ot) {
                floatx4 acc = (floatx4){0.f, 0.f, 0.f, 0.f};
                #pragma unroll
                for (int f = 0; f < 4; ++f) {
                    f16x8 aW = *(const f16x8*)&Ws[ot * 16 + l15][f * 32 + quad * 8];
                    acc = mfma16(aW, xf[f], acc);
                }
                const int ob = zo + ot * 16 + quad * 4;
                ushort4 u;
                u.x = f2h(acc[0] + bias[ob + 0]);
                u.y = f2h(acc[1] + bias[ob + 1]);
                u.z = f2h(acc[2] + bias[ob + 2]);
                u.w = f2h(acc[3] + bias[ob + 3]);
                *(ushort4*)&dst[((size_t)b * NTOT + n0 + w * 16 + l15) * CDIM + ob] = u;
            }
        } else {       // v: C'[n][o], A = X, B = W
            #pragma unroll
            for (int ot = 0; ot < 4; ++ot) {
                floatx4 acc = (floatx4){0.f, 0.f, 0.f, 0.f};
                #pragma unroll
                for (int f = 0; f < 4; ++f) {
                    f16x8 bW = *(const f16x8*)&Ws[ot * 16 + l15][f * 32 + quad * 8];
                    acc = mfma16(xf[f], bW, acc);
                }
                const int o = zo + ot * 16 + l15;
                const float bv_ = bias[o];
                ushort4 u;
                u.x = f2h(acc[0] + bv_); u.y = f2h(acc[1] + bv_);
                u.z = f2h(acc[2] + bv_); u.w = f2h(acc[3] + bv_);
                *(ushort4*)&vo[((size_t)b * CDIM + o) * NTOT + n0 + w * 16 + quad * 4] = u;
            }
        }
    }
}

// ---------------------------------------------------------------------------
// Flash attention, split-K(2) with XCD-aware placement.
// grid: 1-D 512 blocks. xcd = blockIdx.x & 7 -> (b = xcd&3, z = xcd>>2);
// qt = blockIdx.x >> 3. With round-robin blockIdx->XCD dispatch, all 64
// blocks of one (b,z) combo land on ONE XCD; its L2 working set is
// K-half + V-half + Q = ~2 MB < 4 MB -> prefetches hit L2, not HBM.
// Wave w owns queries i = w*16+l15; KT=128 keys/iter, 16 iters per half.
// Ps overlaid on Ks rows 0..63 after barrier C. LDS 69 KB -> 2 blocks/CU.
// Outputs: Op[z][b][i][d] fp16 partials (self-normalized), Ms/Ls stats.
// ---------------------------------------------------------------------------
__global__ __launch_bounds__(256, 2) void attn_kernel(
    const unsigned short* __restrict__ qg,
    const unsigned short* __restrict__ kg,
    const unsigned short* __restrict__ vg,
    unsigned short* __restrict__ Op,
    float* __restrict__ Ms, float* __restrict__ Ls)
{
    __shared__ __align__(16) unsigned short Ks[128 * 136];   // [j][c] 34 KB (rows 0..63 reused as Ps)
    __shared__ __align__(16) unsigned short Vs[128 * 136];   // [d][j] 34 KB

    const int t = threadIdx.x;
    const int w = t >> 6, quad = (t >> 4) & 3, l15 = t & 15;
    const int xcd = blockIdx.x & 7;
    const int b = xcd & 3;
    const int z = xcd >> 2;
    const int i0 = (blockIdx.x >> 3) * 64;
    const int jbase = z * 2048;
    const size_t vbase = (size_t)b * CDIM * NTOT;
    unsigned short* PsW = &Ks[(size_t)w * 16 * 136];   // wave-private P region

    // Q B-fragments direct from global: B[k=c][n=i], i = w*16+l15
    f16x8 bQ[4];
    {
        const size_t qrow = ((size_t)b * NTOT + i0 + w * 16 + l15) * CDIM;
        #pragma unroll
        for (int f = 0; f < 4; ++f)
            bQ[f] = *(const f16x8*)&qg[qrow + f * 32 + quad * 8];
    }

    // prefetch tile 0 into registers
    uint4 bufK[8], bufV[8];
    {
        const size_t kb_ = ((size_t)b * NTOT + jbase) * CDIM;
        #pragma unroll
        for (int r = 0; r < 8; ++r) {
            int flat = r * 256 + t;
            int row = flat >> 4, c16 = (flat & 15) * 8;
            bufK[r] = *(const uint4*)&kg[kb_ + (size_t)row * CDIM + c16];
            bufV[r] = *(const uint4*)&vg[vbase + (size_t)row * NTOT + jbase + c16];
        }
    }

    floatx4 accO[8];
    #pragma unroll
    for (int dt = 0; dt < 8; ++dt) accO[dt] = (floatx4){0.f, 0.f, 0.f, 0.f};
    float m_run = -INFINITY, l_part = 0.f;

    for (int iter = 0; iter < 16; ++iter) {
        __syncthreads();   // (A) prev iter's PV reads of Vs/Ps done
        // commit prefetched tile to LDS
        #pragma unroll
        for (int r = 0; r < 8; ++r) {
            int flat = r * 256 + t;
            int row = flat >> 4, c16 = (flat & 15) * 8;
            *(uint4*)&Ks[row * 136 + c16] = bufK[r];
            *(uint4*)&Vs[row * 136 + c16] = bufV[r];
        }
        __syncthreads();   // (B) tiles ready

        // --- T^T[j][i] = K·Q^T : 8 j-tiles (reads ALL Ks rows) ---
        floatx4 accT[8];
        #pragma unroll
        for (int jt = 0; jt < 8; ++jt) {
            accT[jt] = (floatx4){0.f, 0.f, 0.f, 0.f};
            #pragma unroll
            for (int f = 0; f < 4; ++f) {
                f16x8 aK = *(const f16x8*)&Ks[(jt * 16 + l15) * 136 + f * 32 + quad * 8];
                accT[jt] = mfma16(aK, bQ[f], accT[jt]);
            }
        }

        // --- prefetch next tile (latency hidden behind softmax + PV) ---
        {
            const int jn = jbase + ((iter + 1) & 15) * 128;
            const size_t kb_ = ((size_t)b * NTOT + jn) * CDIM;
            #pragma unroll
            for (int r = 0; r < 8; ++r) {
                int flat = r * 256 + t;
                int row = flat >> 4, c16 = (flat & 15) * 8;
                bufK[r] = *(const uint4*)&kg[kb_ + (size_t)row * CDIM + c16];
                bufV[r] = *(const uint4*)&vg[vbase + (size_t)row * NTOT + jn + c16];
            }
        }

        // --- online softmax (per-lane; lane = one query) ---
        float tm = accT[0][0];
        #pragma unroll
        for (int jt = 0; jt < 8; ++jt)
            #pragma unroll
            for (int r = 0; r < 4; ++r) tm = fmaxf(tm, accT[jt][r]);
        tm = fmaxf(tm, __shfl_xor(tm, 16));
        tm = fmaxf(tm, __shfl_xor(tm, 32));
        const float m_new = fmaxf(m_run, tm);
        const float alpha = __expf(m_run - m_new);   // 0 on first tile
        m_run = m_new;

        float psum = 0.f;
        ushort4 pu[8];   // packed P held in regs until barrier C
        #pragma unroll
        for (int jt = 0; jt < 8; ++jt) {
            float p0 = __expf(accT[jt][0] - m_new);
            float p1 = __expf(accT[jt][1] - m_new);
            float p2 = __expf(accT[jt][2] - m_new);
            float p3 = __expf(accT[jt][3] - m_new);
            psum += (p0 + p1) + (p2 + p3);
            pu[jt].x = f2h(p0); pu[jt].y = f2h(p1);
            pu[jt].z = f2h(p2); pu[jt].w = f2h(p3);
        }
        l_part = l_part * alpha + psum;
        #pragma unroll
        for (int dt = 0; dt < 8; ++dt) {
            accO[dt][0] *= alpha; accO[dt][1] *= alpha;
            accO[dt][2] *= alpha; accO[dt][3] *= alpha;
        }

        __syncthreads();   // (C) all waves' S reads of Ks done -> Ps overlay safe
        #pragma unroll
        for (int jt = 0; jt < 8; ++jt)
            *(ushort4*)&PsW[l15 * 136 + jt * 16 + quad * 4] = pu[jt];

        // --- O^T += V^T·P^T (wave-private P; in-wave lgkmcnt ordering) ---
        f16x8 bP[4];
        #pragma unroll
        for (int kb = 0; kb < 4; ++kb)
            bP[kb] = *(const f16x8*)&PsW[l15 * 136 + kb * 32 + quad * 8];
        #pragma unroll
        for (int dt = 0; dt < 8; ++dt)
            #pragma unroll
            for (int kb = 0; kb < 4; ++kb) {
                f16x8 aV = *(const f16x8*)&Vs[(dt * 16 + l15) * 136 + kb * 32 + quad * 8];
                accO[dt] = mfma16(aV, bP[kb], accO[dt]);
            }
    }

    // final l over quads; store normalized partial + stats
    float lf = l_part;
    lf += __shfl_xor(lf, 16);
    lf += __shfl_xor(lf, 32);
    const float inv = 1.0f / lf;
    const size_t orow = (((size_t)z * 4 + b) * NTOT + i0 + w * 16 + l15) * CDIM;
    #pragma unroll
    for (int dt = 0; dt < 8; ++dt) {
        ushort4 u;
        u.x = f2h(accO[dt][0] * inv); u.y = f2h(accO[dt][1] * inv);
        u.z = f2h(accO[dt][2] * inv); u.w = f2h(accO[dt][3] * inv);
        *(ushort4*)&Op[orow + dt * 16 + quad * 4] = u;
    }
    if (quad == 0) {
        const int idx = (z * 4 + b) * NTOT + i0 + w * 16 + l15;
        Ms[idx] = m_run;
        Ls[idx] = lf;
    }
}

// ---------------------------------------------------------------------------
// Merge the two key-half partials: ao = (w0*O0 + w1*O1), wz = lz*e^{mz-M}/sum.
// grid 1024 x 256 threads, 8 halves (16 B) per thread.
// ---------------------------------------------------------------------------
__global__ __launch_bounds__(256) void combine_kernel(
    const unsigned short* __restrict__ Op,
    const float* __restrict__ Ms, const float* __restrict__ Ls,
    unsigned short* __restrict__ ao)
{
    const int tid = blockIdx.x * 256 + threadIdx.x;     // 0..262143
    const size_t e8 = (size_t)tid * 8;
    const int bn = tid >> 4;                            // b*4096+n (16 thr/row)
    const float m0 = Ms[bn], m1 = Ms[bn + 16384];
    const float l0 = Ls[bn], l1 = Ls[bn + 16384];
    const float M  = fmaxf(m0, m1);
    float w0 = l0 * __expf(m0 - M);
    float w1 = l1 * __expf(m1 - M);
    const float inv = 1.0f / (w0 + w1);
    w0 *= inv; w1 *= inv;

    uint4 a = *(const uint4*)&Op[e8];
    uint4 c = *(const uint4*)&Op[(size_t)2097152 + e8];
    const unsigned short* pa = (const unsigned short*)&a;
    const unsigned short* pc = (const unsigned short*)&c;
    unsigned short ov[8];
    #pragma unroll
    for (int j = 0; j < 8; ++j)
        ov[j] = f2h(w0 * h2f(pa[j]) + w1 * h2f(pc[j]));
    *(uint4*)&ao[e8] = *(const uint4*)ov;
}

// ---------------------------------------------------------------------------
// Output projection + residual, MFMA. ao: [b][n][128] fp16.
// out[b][o][n] = Wo·ao^T + bo + x. grid (64, 4, 2 o-halves), 256 threads.
// ---------------------------------------------------------------------------
__global__ __launch_bounds__(256) void out_proj_kernel(
    const unsigned short* __restrict__ ao,
    const float* __restrict__ Wo, const float* __restrict__ bo,
    const float* __restrict__ x, float* __restrict__ out)
{
    __shared__ __align__(16) unsigned short As[64][136];  // [n][c]
    __shared__ __align__(16) unsigned short Ws[64][136];  // [o-half][c]

    const int t = threadIdx.x, b = blockIdx.y, n0 = blockIdx.x * 64;
    const int zo = blockIdx.z * 64;
    const int w = t >> 6, quad = (t >> 4) & 3, l15 = t & 15;

    #pragma unroll
    for (int r = 0; r < 4; ++r) {   // stage ao tile (direct fp16 copy)
        int flat = r * 256 + t;
        int row = flat >> 4, c16 = (flat & 15) * 8;
        *(uint4*)&As[row][c16] =
            *(const uint4*)&ao[((size_t)b * NTOT + n0 + row) * CDIM + c16];
    }
    {
        int o = t >> 2, ch = (t & 3) * 32;
        #pragma unroll
        for (int i = 0; i < 8; ++i) {
            float4 f4 = *(const float4*)&Wo[(size_t)(zo + o) * CDIM + ch + i * 4];
            ushort4 u = { f2h(f4.x), f2h(f4.y), f2h(f4.z), f2h(f4.w) };
            *(ushort4*)&Ws[o][ch + i * 4] = u;
        }
    }
    __syncthreads();

    f16x8 bA[4];
    #pragma unroll
    for (int f = 0; f < 4; ++f)
        bA[f] = *(const f16x8*)&As[w * 16 + l15][f * 32 + quad * 8];

    #pragma unroll
    for (int ot = 0; ot < 4; ++ot) {
        floatx4 acc = (floatx4){0.f, 0.f, 0.f, 0.f};
        #pragma unroll
        for (int f = 0; f < 4; ++f) {
            f16x8 aW = *(const f16x8*)&Ws[ot * 16 + l15][f * 32 + quad * 8];
            acc = mfma16(aW, bA[f], acc);
        }
        const int ob = zo + ot * 16 + quad * 4;
        #pragma unroll
        for (int r = 0; r < 4; ++r) {
            size_t idx = ((size_t)b * CDIM + ob + r) * NTOT + n0 + w * 16 + l15;
            out[idx] = acc[r] + bo[ob + r] + x[idx];
        }
    }
}

// ---------------------------------------------------------------------------
extern "C" void kernel_launch(void* const* d_in, const int* in_sizes, int n_in,
                              void* d_out, int out_size, void* d_ws, size_t ws_size,
                              hipStream_t stream)
{
    const float* x  = (const float*)d_in[0];
    const float* Wq = (const float*)d_in[1];
    const float* bq = (const float*)d_in[2];
    const float* Wk = (const float*)d_in[3];
    const float* bk = (const float*)d_in[4];
    const float* Wv = (const float*)d_in[5];
    const float* bv = (const float*)d_in[6];
    const float* Wo = (const float*)d_in[7];
    const float* bo = (const float*)d_in[8];
    float* out = (float*)d_out;

    const size_t PER = (size_t)4 * CDIM * NTOT;   // 2,097,152 elements
    unsigned short* q_ws  = (unsigned short*)d_ws;
    unsigned short* k_ws  = q_ws + PER;
    unsigned short* v_ws  = k_ws + PER;
    unsigned short* ao_ws = v_ws + PER;           // fp16 [b][n][c]
    unsigned short* op_ws = ao_ws + PER;          // fp16 [2][b][n][c] partials
    float*          ms_ws = (float*)(op_ws + 2 * PER);   // [2][b*n]
    float*          ls_ws = ms_ws + 2 * 16384;

    dim3 blk(256);
    qkv_proj_kernel<<<dim3(64, 4, 2), blk, 0, stream>>>(
        x, Wq, bq, Wk, bk, Wv, bv, q_ws, k_ws, v_ws);
    attn_kernel<<<dim3(512), blk, 0, stream>>>(
        q_ws, k_ws, v_ws, op_ws, ms_ws, ls_ws);
    combine_kernel<<<dim3(1024), blk, 0, stream>>>(op_ws, ms_ws, ls_ws, ao_ws);
    out_proj_kernel<<<dim3(64, 4, 2), blk, 0, stream>>>(ao_ws, Wo, bo, x, out);
}